// Round 5
// baseline (249.836 us; speedup 1.0000x reference)
//
#include <hip/hip_runtime.h>
#include <hip/hip_bf16.h>

// MultiHeadAttention_1580547974647 — MI355X gfx950
// B=2, L=2048, D=1024, H=16, DT=64.
//   Qs[h] = head block of Qproj viewed (2048 x 64);  KT[h] (2048 x 64) pre-transposed
//   Vs[h] = head block viewed (2048 x 64);           VT[h] (64 x 2048) pre-transposed
//   softmax over the HEAD axis; concat is the inverse view.
// R18: GEMMs retiled to 128x128 @ 512 threads. Attn 2-barrier, 104-108us.
// R19 (REVERTED): LDS atomicAdd head-sums -> 7x regression (atomics serialize).
// R20 (NEUTRAL): uniform sum phase + V-load hoist. Attn is barrier/latency-bound.
// R21 (REVERTED): i-tile 32 / 2-blocks-per-CU: occupancy register-pinned at
//      16 waves/CU (VGPR+AGPR ~128/lane); smaller tile only added overhead.
// R22 (REVERTED): 1-barrier dbuf schedule: +20MB writes (spill suspect),
//      MfmaUtil down, 131us. 2-barrier sum-between is the local optimum.
// R23: amortize the per-barrier-pair fixed cost (~9k cyc vs ~7k work at
//      j-tile 32): j-tile 32 -> 64 as two sequential 32-wide halves (register
//      peak unchanged; kf/vf reused). Barriers per j-sweep halved. LDS
//      expS[16][64][32]+rcpS = 136 KB, 1 block/CU (already reg-pinned).
//      Sum phase: 2 physical words/thread, fx-XOR lane map -> 2-way banks.

using u16   = unsigned short;
using f16   = _Float16;
using f16x2 = _Float16 __attribute__((ext_vector_type(2)));
using f16x8 = _Float16 __attribute__((ext_vector_type(8)));
using bf16x8 = __bf16 __attribute__((ext_vector_type(8)));
using f32x4  = float  __attribute__((ext_vector_type(4)));

__device__ __forceinline__ u16 f2bf(float f) {          // native RNE cast
    __bf16 h = (__bf16)f;
    return __builtin_bit_cast(u16, h);
}
__device__ __forceinline__ float ex2(float x) {          // 2^x (v_exp_f32)
    return __builtin_amdgcn_exp2f(x);
}
__device__ __forceinline__ bf16x8 ldfrag(const u16* p) {   // 16B aligned
    bf16x8 r; __builtin_memcpy(&r, p, 16); return r;
}
__device__ __forceinline__ f16x8 ldfrag16(const u16* p) {  // 16B aligned
    f16x8 r; __builtin_memcpy(&r, p, 16); return r;
}
__device__ __forceinline__ unsigned pkrtz(float a, float b) {
    return __builtin_bit_cast(unsigned, __builtin_amdgcn_cvt_pkrtz(a, b));
}
__device__ __forceinline__ f16x2 u2h(unsigned u) { return __builtin_bit_cast(f16x2, u); }
__device__ __forceinline__ unsigned h2u(f16x2 h) { return __builtin_bit_cast(unsigned, h); }

__device__ __forceinline__ void stage16(const float* p, u16* d) {
    #pragma unroll
    for (int u = 0; u < 16; u += 4) {
        float4 t = *reinterpret_cast<const float4*>(p + u);
        d[u + 0] = f2bf(t.x); d[u + 1] = f2bf(t.y);
        d[u + 2] = f2bf(t.z); d[u + 3] = f2bf(t.w);
    }
}
__device__ __forceinline__ void stage16(const u16* p, u16* d) {
    #pragma unroll
    for (int u = 0; u < 16; u += 8)
        *reinterpret_cast<uint4*>(d + u) = *reinterpret_cast<const uint4*>(p + u);
}
// NS-source staging: d = bf16(sum of NS bf16 streams)
template <int NS>
__device__ __forceinline__ void stage16s(const u16* a, const u16* b,
                                         const u16* c, const u16* d2, u16* dst) {
    #pragma unroll
    for (int u = 0; u < 16; u += 8) {
        bf16x8 va = ldfrag(a + u), vb, vc, vd;
        if constexpr (NS >= 2) vb = ldfrag(b + u);
        if constexpr (NS >= 3) vc = ldfrag(c + u);
        if constexpr (NS >= 4) vd = ldfrag(d2 + u);
        #pragma unroll
        for (int e = 0; e < 8; ++e) {
            float s = (float)va[e];
            if constexpr (NS >= 2) s += (float)vb[e];
            if constexpr (NS >= 3) s += (float)vc[e];
            if constexpr (NS >= 4) s += (float)vd[e];
            dst[u + e] = f2bf(s);
        }
    }
}

// ---------------------------------------------------------------------------
// Shared GEMM tile body (R18): 128x128 (BMxBN), BK=64, 512 threads = 8 waves
// (2m x 4n), each wave 64x32 out (acc[4][2] = 32 AGPR). Staging: each thread
// 16 X-elems + 16 W-elems per k-tile (rows tid>>2 = 0..127 of both tiles).
// XT = float or u16 (bf16); output: F16O ? f16 : (u16 ? bf16 : f32).
// ---------------------------------------------------------------------------
template <typename XT, typename OT, int NS, bool F16O>
__device__ __forceinline__ void gemm_body(
    const XT* __restrict__ X, const XT* __restrict__ X2,
    const XT* __restrict__ X3, const XT* __restrict__ X4,
    const float* __restrict__ W, const float* __restrict__ bias,
    OT* __restrict__ C, float scale,
    u16 (*lX)[72], u16 (*lW)[72])
{
    const int tid  = threadIdx.x;
    const int lane = tid & 63;
    const int wv   = tid >> 6;          // 0..7
    const int wm   = (wv >> 2) * 64;    // 0 or 64
    const int wn   = (wv & 3) * 32;     // 0,32,64,96
    const int m0 = blockIdx.x * 128;
    const int n0 = blockIdx.y * 128;
    const int sr = tid >> 2;            // 0..127
    const int sq = (tid & 3) * 16;
    const int fm = lane & 15;
    const int g  = lane >> 4;
    const int fk = g * 8;

    f32x4 acc[4][2] = {};

    for (int k0 = 0; k0 < 1024; k0 += 64) {
        {
            const size_t xo = (size_t)(m0 + sr) * 1024 + k0 + sq;
            if constexpr (NS > 1)
                stage16s<NS>(X + xo, X2 + xo, X3 + xo, X4 + xo, &lX[sr][sq]);
            else
                stage16(X + xo, &lX[sr][sq]);
        }
        stage16(W + (size_t)(n0 + sr) * 1024 + k0 + sq, &lW[sr][sq]);
        __syncthreads();
        #pragma unroll
        for (int kb = 0; kb < 2; ++kb) {
            bf16x8 a[4], bb[2];
            #pragma unroll
            for (int mb = 0; mb < 4; ++mb)
                a[mb] = ldfrag(&lX[wm + mb * 16 + fm][kb * 32 + fk]);
            #pragma unroll
            for (int nb = 0; nb < 2; ++nb)
                bb[nb] = ldfrag(&lW[wn + nb * 16 + fm][kb * 32 + fk]);
            #pragma unroll
            for (int mb = 0; mb < 4; ++mb)
                #pragma unroll
                for (int nb = 0; nb < 2; ++nb)
                    acc[mb][nb] = __builtin_amdgcn_mfma_f32_16x16x32_bf16(
                        a[mb], bb[nb], acc[mb][nb], 0, 0, 0);
        }
        __syncthreads();
    }

    #pragma unroll
    for (int mb = 0; mb < 4; ++mb) {
        #pragma unroll
        for (int nb = 0; nb < 2; ++nb) {
            const int row = m0 + wm + mb * 16 + g * 4;
            const int col = n0 + wn + nb * 16 + fm;
            const float bv = bias[col];
            #pragma unroll
            for (int r = 0; r < 4; ++r) {
                const float val = (acc[mb][nb][r] + bv) * scale;
                OT* p = C + (size_t)(row + r) * 1024 + col;
                if constexpr (F16O) {
                    f16 h = (f16)val;
                    *p = __builtin_bit_cast(u16, h);
                } else if constexpr (__is_same(OT, u16)) {
                    *p = f2bf(val);
                } else {
                    *p = val;
                }
            }
        }
    }
}

// ---------------------------------------------------------------------------
// Fused Q/K/V projection: grid (32, 8, 3); z selects input/weights/output.
// Q gets scale = 1/8 * log2(e); outputs f16.
// ---------------------------------------------------------------------------
__global__ __launch_bounds__(512) void gemm_qkv(
    const float* __restrict__ q, const float* __restrict__ k,
    const float* __restrict__ v,
    const float* __restrict__ Wq, const float* __restrict__ bq,
    const float* __restrict__ Wk, const float* __restrict__ bk,
    const float* __restrict__ Wv, const float* __restrict__ bv,
    u16* __restrict__ Q16, u16* __restrict__ K16, u16* __restrict__ V16,
    float qscale)
{
    __shared__ u16 lX[128][72];
    __shared__ u16 lW[128][72];
    const int z = blockIdx.z;
    const float* X = (z == 0) ? q  : (z == 1) ? k  : v;
    const float* W = (z == 0) ? Wq : (z == 1) ? Wk : Wv;
    const float* B = (z == 0) ? bq : (z == 1) ? bk : bv;
    u16*         C = (z == 0) ? Q16 : (z == 1) ? K16 : V16;
    const float  s = (z == 0) ? qscale : 1.0f;
    gemm_body<float, u16, 1, true>(X, nullptr, nullptr, nullptr, W, B, C, s, lX, lW);
}

// ---------------------------------------------------------------------------
// Final projection: C = (sum of NS partial-O bf16 streams) @ Wc^T + bc, f32 out.
// ---------------------------------------------------------------------------
template <int NS>
__global__ __launch_bounds__(512) void gemm_final(
    const u16* __restrict__ X, const u16* __restrict__ X2,
    const u16* __restrict__ X3, const u16* __restrict__ X4,
    const float* __restrict__ W, const float* __restrict__ bias,
    float* __restrict__ C)
{
    __shared__ u16 lX[128][72];
    __shared__ u16 lW[128][72];
    gemm_body<u16, float, NS, false>(X, X2, X3, X4, W, bias, C, 1.0f, lX, lW);
}

// ---------------------------------------------------------------------------
// Fused K+V transpose: grid 2048 blocks; blocks [0,1024) transpose K
// (-> KT), blocks [1024,2048) transpose V (-> VT). Tiled XOR-swizzled LDS.
// ---------------------------------------------------------------------------
__global__ __launch_bounds__(256) void tp_kv2(
    const u16* __restrict__ kin, u16* __restrict__ kout,
    const u16* __restrict__ vin, u16* __restrict__ vout)
{
    __shared__ u16 t[64][80];
    const int which = (blockIdx.x >> 10) & 1;
    const int bx    = blockIdx.x & 1023;
    const u16* in_  = which ? vin  : kin;
    u16*       out_ = which ? vout : kout;
    const int tid = threadIdx.x;
    const int bh  = bx >> 5;
    const int tt  = bx & 31;
    const size_t base = (size_t)bh * 131072;
    const int C         = which ? 64 : 2048;
    const int r0        = which ? tt * 64 : 0;
    const int c0        = which ? 0 : tt * 64;
    const int outstride = which ? 2048 : 64;
    const u16* in = in_ + base;
    u16* out      = out_ + base;

    #pragma unroll
    for (int half = 0; half < 2; ++half) {
        const int rr = (tid >> 3) + half * 32;
        const int cb = tid & 7;
        const int cbs = cb ^ ((rr >> 3) & 7);
        *reinterpret_cast<uint4*>(&t[rr][cbs * 8]) =
            *reinterpret_cast<const uint4*>(in + (size_t)(r0 + rr) * C + c0 + cb * 8);
    }
    __syncthreads();
    #pragma unroll
    for (int half = 0; half < 2; ++half) {
        const int c  = (tid >> 3) + half * 32;
        const int rb = tid & 7;
        u16 vv[8];
        #pragma unroll
        for (int e = 0; e < 8; ++e) {
            const int r = rb * 8 + e;
            const int cbs2 = (c >> 3) ^ ((r >> 3) & 7);
            vv[e] = t[r][cbs2 * 8 + (c & 7)];
        }
        *reinterpret_cast<uint4*>(out + (size_t)(c0 + c) * outstride + r0 + rb * 8) =
            *reinterpret_cast<uint4*>(vv);
    }
}

// ---------------------------------------------------------------------------
// Fused attention (R23). 1024 threads = 16 waves, wave w = head w.
// i-tile 64, j-tile 64 (two sequential 32-wide halves), 2-barrier schedule,
// exp2 builtin, packed-f16 softmax. LDS expS[16][64][32] (128 KB) +
// rcpS[64][32] (8 KB) = 136 KB. XOR swizzle fx(row) = ((row>>1)&3)<<2 on the
// word index (multiple of 4 -> b64/b128 contiguity preserved).
// ---------------------------------------------------------------------------
__global__ __launch_bounds__(1024) void attn_fused(
    const u16* __restrict__ Qb, const u16* __restrict__ KT,
    const u16* __restrict__ VT, u16* __restrict__ O0,
    u16* __restrict__ O1, u16* __restrict__ O2, u16* __restrict__ O3,
    int jsplit)
{
    __shared__ unsigned expS[16][64][32];  // [head][i][jword] f16x2, swizzled (128 KB)
    __shared__ unsigned rcpS[64][32];      // [i][jword] f16x2 of 1/sum (8 KB)

    const int tid  = threadIdx.x;
    const int w    = tid >> 6;        // head
    const int lane = tid & 63;
    const int fm   = lane & 15;
    const int g    = lane >> 4;
    const int fk   = g * 8;
    const int g4   = g * 4;
    const int g2   = g * 2;

    int b, it, js;
    u16* Ob;
    if (jsplit == 4) {
        const int grp = blockIdx.x & 7;
        b  = grp >> 2;
        js = grp & 3;
        it = blockIdx.x >> 3;                 // 0..31
        Ob = (js == 0) ? O0 : (js == 1) ? O1 : (js == 2) ? O2 : O3;
    } else if (jsplit == 2) {
        const int grp = blockIdx.x & 3;
        b  = grp >> 1;
        js = grp & 1;
        it = blockIdx.x >> 2;
        Ob = js ? O1 : O0;
    } else {
        b  = blockIdx.x >> 5;
        it = blockIdx.x & 31;
        js = 0;
        Ob = O0;
    }
    const int jlen  = 2048 / jsplit;
    const int jbase = js * jlen;
    const int i0    = it * 64;
    const size_t hb = ((size_t)b * 2048 + (size_t)w * 128) * 1024;

    // per-row LDS word swizzle (multiple of 4 -> keeps b64/b128 contiguity;
    // < 16 -> commutes with the +16 half offset)
    auto fx = [](int r) { return ((r >> 1) & 3) << 2; };

    // Q fragments (f16): 4 m-blocks x 2 k-steps (loop-invariant)
    f16x8 qa[4][2];
    #pragma unroll
    for (int m = 0; m < 4; ++m)
        #pragma unroll
        for (int kb = 0; kb < 2; ++kb)
            qa[m][kb] = ldfrag16(Qb + hb + (size_t)(i0 + m * 16 + fm) * 64 + kb * 32 + fk);

    f32x4 oacc[4][4] = {};   // 64 x 64 O tile per wave

    const int nt = jlen >> 6;   // 64-wide j-tiles

    // ---- QK for a 32-j half -> E writes into word cols [cb, cb+16) ----
    auto qk_half = [&](int j0, int cb) {
        f16x8 kf[2][2];
        #pragma unroll
        for (int kb = 0; kb < 2; ++kb)
            #pragma unroll
            for (int nb = 0; nb < 2; ++nb)
                kf[kb][nb] = ldfrag16(KT + hb + (size_t)(j0 + nb * 16 + fm) * 64
                                               + kb * 32 + fk);
        #pragma unroll
        for (int m = 0; m < 4; ++m) {
            f32x4 st[2] = {};
            #pragma unroll
            for (int kb = 0; kb < 2; ++kb)
                #pragma unroll
                for (int nb = 0; nb < 2; ++nb)
                    st[nb] = __builtin_amdgcn_mfma_f32_16x16x32_f16(
                        kf[kb][nb], qa[m][kb], st[nb], 0, 0, 0);
            const int row = m * 16 + fm;
            const int fr  = fx(row);
            #pragma unroll
            for (int nb = 0; nb < 2; ++nb) {
                uint2 ew2;
                ew2.x = pkrtz(ex2(st[nb][0]), ex2(st[nb][1]));
                ew2.y = pkrtz(ex2(st[nb][2]), ex2(st[nb][3]));
                *reinterpret_cast<uint2*>(&expS[w][row][(cb + nb * 8 + g2) ^ fr]) = ew2;
            }
        }
    };

    // ---- PV for a 32-j half (word cols [cb, cb+16)), V at col jh ----
    auto pv_half = [&](int jh, int cb) {
        f16x8 vf[4];
        #pragma unroll
        for (int nb = 0; nb < 4; ++nb)
            vf[nb] = ldfrag16(VT + hb + (size_t)(nb * 16 + fm) * 2048 + jh + fk);
        #pragma unroll
        for (int m = 0; m < 4; ++m) {
            const int row = m * 16 + fm;
            const int fr  = fx(row);
            const uint4 ew = *reinterpret_cast<const uint4*>(&expS[w][row][(cb + g4) ^ fr]);
            const uint4 rw = *reinterpret_cast<const uint4*>(&rcpS[row][(cb + g4) ^ fr]);
            uint4 pw;
            pw.x = h2u(u2h(ew.x) * u2h(rw.x));
            pw.y = h2u(u2h(ew.y) * u2h(rw.y));
            pw.z = h2u(u2h(ew.z) * u2h(rw.z));
            pw.w = h2u(u2h(ew.w) * u2h(rw.w));
            const f16x8 pa = __builtin_bit_cast(f16x8, pw);
            #pragma unroll
            for (int nb = 0; nb < 4; ++nb)
                oacc[m][nb] = __builtin_amdgcn_mfma_f32_16x16x32_f16(
                    pa, vf[nb], oacc[m][nb], 0, 0, 0);
        }
    };

    // prologue: E(0) for both halves
    qk_half(jbase, 0);
    qk_half(jbase + 32, 16);

    for (int t = 0; t < nt; ++t) {
        const int j0 = jbase + (t << 6);
        __syncthreads();   // E(t) complete
        // ---- cross-head sum: all 1024 threads, 2 physical words each ----
        {
            const int i = tid >> 4;                 // 0..63
            const int p = (tid & 15) ^ fx(i);       // physical word, half A
            unsigned e0[16], e1[16];
            #pragma unroll
            for (int h = 0; h < 16; ++h) {
                e0[h] = expS[h][i][p];
                e1[h] = expS[h][i][p + 16];
            }
            const f16x2 a0 = ((u2h(e0[0])  + u2h(e0[1]))  + (u2h(e0[2])  + u2h(e0[3])))
                           + ((u2h(e0[4])  + u2h(e0[5]))  + (u2h(e0[6])  + u2h(e0[7])));
            const f16x2 a1 = ((u2h(e0[8])  + u2h(e0[9]))  + (u2h(e0[10]) + u2h(e0[11])))
                           + ((u2h(e0[12]) + u2h(e0[13])) + (u2h(e0[14]) + u2h(e0[15])));
            const f16x2 ta = a0 + a1;
            const f16x2 b0 = ((u2h(e1[0])  + u2h(e1[1]))  + (u2h(e1[2])  + u2h(e1[3])))
                           + ((u2h(e1[4])  + u2h(e1[5]))  + (u2h(e1[6])  + u2h(e1[7])));
            const f16x2 b1 = ((u2h(e1[8])  + u2h(e1[9]))  + (u2h(e1[10]) + u2h(e1[11])))
                           + ((u2h(e1[12]) + u2h(e1[13])) + (u2h(e1[14]) + u2h(e1[15])));
            const f16x2 tb = b0 + b1;
            rcpS[i][p]      = pkrtz(__builtin_amdgcn_rcpf((float)ta[0]),
                                    __builtin_amdgcn_rcpf((float)ta[1]));
            rcpS[i][p + 16] = pkrtz(__builtin_amdgcn_rcpf((float)tb[0]),
                                    __builtin_amdgcn_rcpf((float)tb[1]));
        }
        __syncthreads();   // rcp(t) ready
        // ---- PV both halves (vf reused; accumulate over j into oacc) ----
        pv_half(j0, 0);
        pv_half(j0 + 32, 16);
        // ---- QK(t+1) both halves (own-wave slab; after own E reads) ----
        if (t + 1 < nt) {
            qk_half(j0 + 64, 0);
            qk_half(j0 + 96, 16);
        }
    }

    // ---- write O (block-view layout) as bf16 for the final projection ----
    #pragma unroll
    for (int m = 0; m < 4; ++m)
        #pragma unroll
        for (int nb = 0; nb < 4; ++nb)
            #pragma unroll
            for (int r = 0; r < 4; ++r) {
                const int i = i0 + m * 16 + g4 + r;
                Ob[hb + (size_t)i * 64 + nb * 16 + fm] = f2bf(oacc[m][nb][r]);
            }
}

// ---------------------------------------------------------------------------
extern "C" void kernel_launch(void* const* d_in, const int* in_sizes, int n_in,
                              void* d_out, int out_size, void* d_ws, size_t ws_size,
                              hipStream_t stream)
{
    const float* q  = (const float*)d_in[0];
    const float* k  = (const float*)d_in[1];
    const float* v  = (const float*)d_in[2];
    const float* Wq = (const float*)d_in[3];
    const float* bq = (const float*)d_in[4];
    const float* Wk = (const float*)d_in[5];
    const float* bk = (const float*)d_in[6];
    const float* Wv = (const float*)d_in[7];
    const float* bv = (const float*)d_in[8];
    const float* Wc = (const float*)d_in[9];
    const float* bc = (const float*)d_in[10];
    float* out = (float*)d_out;

    const size_t MD = (size_t)4096 * 1024;   // elements per [B*L, D] matrix
    u16* W0 = (u16*)d_ws;        // Q16
    u16* W1 = W0 + MD;           // K16 -> O0
    u16* W2 = W1 + MD;           // V16 -> O1
    u16* W3 = W2 + MD;           // KT
    u16* W4 = W3 + MD;           // VT
    u16* W5 = W4 + MD;           // O2
    u16* W6 = W5 + MD;           // O3

    int jsplit = 1;
    if      (ws_size >= 7 * MD * sizeof(u16)) jsplit = 4;   // 56 MB
    else if (ws_size >= 5 * MD * sizeof(u16)) jsplit = 2;   // 40 MB

    // Q scale = 1/8 (score scale) * log2(e) (exp -> exp2 folding)
    const float qscale = 0.125f * 1.4426950408889634f;

    // (1) fused QKV projections: grid (32,8,3), 512 threads
    gemm_qkv<<<dim3(32, 8, 3), dim3(512), 0, stream>>>(
        q, k, v, Wq, bq, Wk, bk, Wv, bv, W0, W1, W2, qscale);
    // (2) fused K+V transpose
    tp_kv2<<<dim3(2048), dim3(256), 0, stream>>>(W1, W3, W2, W4);
    // (3) attention
    const int agrid = (jsplit == 4) ? 256 : (jsplit == 2) ? 128 : 64;
    attn_fused<<<dim3(agrid), dim3(1024), 0, stream>>>(
        W0, W3, W4, W1, W2, W5, W6, jsplit);
    // (4) final projection (+ partial-O summation)
    if (jsplit == 4)
        gemm_final<4><<<dim3(32, 8), dim3(512), 0, stream>>>(W1, W2, W5, W6, Wc, bc, out);
    else if (jsplit == 2)
        gemm_final<2><<<dim3(32, 8), dim3(512), 0, stream>>>(W1, W2, nullptr, nullptr, Wc, bc, out);
    else
        gemm_final<1><<<dim3(32, 8), dim3(512), 0, stream>>>(W1, nullptr, nullptr, nullptr, Wc, bc, out);
}

// Round 6
// 184.199 us; speedup vs baseline: 1.3563x; 1.3563x over previous
//
#include <hip/hip_runtime.h>
#include <hip/hip_bf16.h>

// MultiHeadAttention_1580547974647 — MI355X gfx950
// B=2, L=2048, D=1024, H=16, DT=64.
//   Qs[h] = head block of Qproj viewed (2048 x 64);  KT[h] (2048 x 64) pre-transposed
//   Vs[h] = head block viewed (2048 x 64);           VT[h] (64 x 2048) pre-transposed
//   softmax over the HEAD axis; concat is the inverse view.
// R18: GEMMs 128x128 @ 512 thr. Attn 2-barrier, 104-108us. 4 dispatches.
// R19 (REVERTED): LDS atomicAdd head-sums -> 7x (LDS atomics serialize).
// R20 (kept): uniform sum + V-hoist, neutral; attn = barrier/latency local opt.
// R21 (REVERTED): 2-blocks/CU: register-pinned (VGPR+AGPR unified ~128/lane).
// R22 (REVERTED): 1-barrier dbuf: spills (+20MB writes), 131us.
// R23 (REVERTED): j-tile 64: 32 extra live regs -> 190MB spill traffic, 145us.
//   => attn FROZEN at R20 (107.5us). Any wider live state spills.
// R24: GEMM-side consolidation. (a) prep: one-pass f32->bf16 convert of
//      q,k,v,Wq,Wk,Wv,Wc (layered: only if ws>=88MB) -> both GEMMs stage raw
//      uint4 copies, no per-k-tile cvt. (b) presum: fold the 4 partial-O
//      streams once (into dead Q16 buffer, no extra ws) -> gemm_final is
//      always NS=1. Numerics identical (same f32-sum -> bf16 rounding).

using u16   = unsigned short;
using f16   = _Float16;
using f16x2 = _Float16 __attribute__((ext_vector_type(2)));
using f16x8 = _Float16 __attribute__((ext_vector_type(8)));
using bf16x8 = __bf16 __attribute__((ext_vector_type(8)));
using f32x4  = float  __attribute__((ext_vector_type(4)));

__device__ __forceinline__ u16 f2bf(float f) {          // native RNE cast
    __bf16 h = (__bf16)f;
    return __builtin_bit_cast(u16, h);
}
__device__ __forceinline__ float ex2(float x) {          // 2^x (v_exp_f32)
    return __builtin_amdgcn_exp2f(x);
}
__device__ __forceinline__ bf16x8 ldfrag(const u16* p) {   // 16B aligned
    bf16x8 r; __builtin_memcpy(&r, p, 16); return r;
}
__device__ __forceinline__ f16x8 ldfrag16(const u16* p) {  // 16B aligned
    f16x8 r; __builtin_memcpy(&r, p, 16); return r;
}
__device__ __forceinline__ unsigned pkrtz(float a, float b) {
    return __builtin_bit_cast(unsigned, __builtin_amdgcn_cvt_pkrtz(a, b));
}
__device__ __forceinline__ f16x2 u2h(unsigned u) { return __builtin_bit_cast(f16x2, u); }
__device__ __forceinline__ unsigned h2u(f16x2 h) { return __builtin_bit_cast(unsigned, h); }

__device__ __forceinline__ void stage16(const float* p, u16* d) {
    #pragma unroll
    for (int u = 0; u < 16; u += 4) {
        float4 t = *reinterpret_cast<const float4*>(p + u);
        d[u + 0] = f2bf(t.x); d[u + 1] = f2bf(t.y);
        d[u + 2] = f2bf(t.z); d[u + 3] = f2bf(t.w);
    }
}
__device__ __forceinline__ void stage16(const u16* p, u16* d) {
    #pragma unroll
    for (int u = 0; u < 16; u += 8)
        *reinterpret_cast<uint4*>(d + u) = *reinterpret_cast<const uint4*>(p + u);
}

// ---------------------------------------------------------------------------
// Shared GEMM tile body: 128x128 (BMxBN), BK=64, 512 threads = 8 waves
// (2m x 4n), each wave 64x32 out (acc[4][2] = 32 AGPR). Staging: each thread
// 16 X-elems + 16 W-elems per k-tile. XT/WT = float (cvt staging) or u16
// (raw bf16 copy). Output: F16O ? f16 : (u16 ? bf16 : f32).
// ---------------------------------------------------------------------------
template <typename XT, typename WT, typename OT, bool F16O>
__device__ __forceinline__ void gemm_body(
    const XT* __restrict__ X,
    const WT* __restrict__ W, const float* __restrict__ bias,
    OT* __restrict__ C, float scale,
    u16 (*lX)[72], u16 (*lW)[72])
{
    const int tid  = threadIdx.x;
    const int lane = tid & 63;
    const int wv   = tid >> 6;          // 0..7
    const int wm   = (wv >> 2) * 64;    // 0 or 64
    const int wn   = (wv & 3) * 32;     // 0,32,64,96
    const int m0 = blockIdx.x * 128;
    const int n0 = blockIdx.y * 128;
    const int sr = tid >> 2;            // 0..127
    const int sq = (tid & 3) * 16;
    const int fm = lane & 15;
    const int g  = lane >> 4;
    const int fk = g * 8;

    f32x4 acc[4][2] = {};

    for (int k0 = 0; k0 < 1024; k0 += 64) {
        stage16(X + (size_t)(m0 + sr) * 1024 + k0 + sq, &lX[sr][sq]);
        stage16(W + (size_t)(n0 + sr) * 1024 + k0 + sq, &lW[sr][sq]);
        __syncthreads();
        #pragma unroll
        for (int kb = 0; kb < 2; ++kb) {
            bf16x8 a[4], bb[2];
            #pragma unroll
            for (int mb = 0; mb < 4; ++mb)
                a[mb] = ldfrag(&lX[wm + mb * 16 + fm][kb * 32 + fk]);
            #pragma unroll
            for (int nb = 0; nb < 2; ++nb)
                bb[nb] = ldfrag(&lW[wn + nb * 16 + fm][kb * 32 + fk]);
            #pragma unroll
            for (int mb = 0; mb < 4; ++mb)
                #pragma unroll
                for (int nb = 0; nb < 2; ++nb)
                    acc[mb][nb] = __builtin_amdgcn_mfma_f32_16x16x32_bf16(
                        a[mb], bb[nb], acc[mb][nb], 0, 0, 0);
        }
        __syncthreads();
    }

    #pragma unroll
    for (int mb = 0; mb < 4; ++mb) {
        #pragma unroll
        for (int nb = 0; nb < 2; ++nb) {
            const int row = m0 + wm + mb * 16 + g * 4;
            const int col = n0 + wn + nb * 16 + fm;
            const float bv = bias[col];
            #pragma unroll
            for (int r = 0; r < 4; ++r) {
                const float val = (acc[mb][nb][r] + bv) * scale;
                OT* p = C + (size_t)(row + r) * 1024 + col;
                if constexpr (F16O) {
                    f16 h = (f16)val;
                    *p = __builtin_bit_cast(u16, h);
                } else if constexpr (__is_same(OT, u16)) {
                    *p = f2bf(val);
                } else {
                    *p = val;
                }
            }
        }
    }
}

// ---------------------------------------------------------------------------
// Fused Q/K/V projection: grid (32, 8, 3); z selects input/weights/output.
// T = float (direct f32 inputs) or u16 (pre-converted bf16 inputs).
// Q gets scale = 1/8 * log2(e); outputs f16.
// ---------------------------------------------------------------------------
template <typename T>
__global__ __launch_bounds__(512) void gemm_qkv_t(
    const T* __restrict__ q, const T* __restrict__ k,
    const T* __restrict__ v,
    const T* __restrict__ Wq, const float* __restrict__ bq,
    const T* __restrict__ Wk, const float* __restrict__ bk,
    const T* __restrict__ Wv, const float* __restrict__ bv,
    u16* __restrict__ Q16, u16* __restrict__ K16, u16* __restrict__ V16,
    float qscale)
{
    __shared__ u16 lX[128][72];
    __shared__ u16 lW[128][72];
    const int z = blockIdx.z;
    const T* X = (z == 0) ? q  : (z == 1) ? k  : v;
    const T* W = (z == 0) ? Wq : (z == 1) ? Wk : Wv;
    const float* B = (z == 0) ? bq : (z == 1) ? bk : bv;
    u16*         C = (z == 0) ? Q16 : (z == 1) ? K16 : V16;
    const float  s = (z == 0) ? qscale : 1.0f;
    gemm_body<T, T, u16, true>(X, W, B, C, s, lX, lW);
}

// ---------------------------------------------------------------------------
// Final projection: C = X @ Wc^T + bc, f32 out. X is the (pre-summed) bf16
// O matrix; WT = float (raw Wc) or u16 (pre-converted bf16 Wc).
// ---------------------------------------------------------------------------
template <typename WT>
__global__ __launch_bounds__(512) void gemm_final_t(
    const u16* __restrict__ X,
    const WT* __restrict__ W, const float* __restrict__ bias,
    float* __restrict__ C)
{
    __shared__ u16 lX[128][72];
    __shared__ u16 lW[128][72];
    gemm_body<u16, WT, float, false>(X, W, bias, C, 1.0f, lX, lW);
}

// ---------------------------------------------------------------------------
// prep: one-pass f32 -> bf16 convert of q,k,v (4M elems each) and the four
// 1M-elem weight matrices. Grid-stride over 8-element chunks.
// ---------------------------------------------------------------------------
__global__ __launch_bounds__(256) void prep_bf16(
    const float* __restrict__ q, const float* __restrict__ k,
    const float* __restrict__ v,
    const float* __restrict__ Wq, const float* __restrict__ Wk,
    const float* __restrict__ Wv, const float* __restrict__ Wc,
    u16* __restrict__ qb, u16* __restrict__ kb, u16* __restrict__ vb,
    u16* __restrict__ wqb, u16* __restrict__ wkb,
    u16* __restrict__ wvb, u16* __restrict__ wcb)
{
    const long long NC = 2097152;   // 16M elems / 8
    for (long long c = (long long)blockIdx.x * 256 + threadIdx.x; c < NC;
         c += (long long)gridDim.x * 256) {
        const float* src; u16* dst; long long off;
        if (c < 1572864) {
            if (c < 524288)       { src = q; dst = qb; off = c; }
            else if (c < 1048576) { src = k; dst = kb; off = c - 524288; }
            else                  { src = v; dst = vb; off = c - 1048576; }
        } else {
            const long long wI = c - 1572864;
            if (wI < 131072)      { src = Wq; dst = wqb; off = wI; }
            else if (wI < 262144) { src = Wk; dst = wkb; off = wI - 131072; }
            else if (wI < 393216) { src = Wv; dst = wvb; off = wI - 262144; }
            else                  { src = Wc; dst = wcb; off = wI - 393216; }
        }
        const float* p = src + off * 8;
        const float4 a  = reinterpret_cast<const float4*>(p)[0];
        const float4 b2 = reinterpret_cast<const float4*>(p)[1];
        u16 d[8];
        d[0] = f2bf(a.x);  d[1] = f2bf(a.y);  d[2] = f2bf(a.z);  d[3] = f2bf(a.w);
        d[4] = f2bf(b2.x); d[5] = f2bf(b2.y); d[6] = f2bf(b2.z); d[7] = f2bf(b2.w);
        *reinterpret_cast<uint4*>(dst + off * 8) = *reinterpret_cast<uint4*>(d);
    }
}

// ---------------------------------------------------------------------------
// presum: o = bf16(sum of NS bf16 partial-O streams), 4M elems.
// Same f32-accumulate -> bf16 rounding as the old in-GEMM stage16s.
// ---------------------------------------------------------------------------
template <int NS>
__global__ __launch_bounds__(256) void presum_o(
    const u16* __restrict__ a, const u16* __restrict__ b,
    const u16* __restrict__ c, const u16* __restrict__ d,
    u16* __restrict__ o)
{
    const long long NC = 524288;    // 4M elems / 8
    for (long long i = (long long)blockIdx.x * 256 + threadIdx.x; i < NC;
         i += (long long)gridDim.x * 256) {
        const long long e0 = i * 8;
        const bf16x8 va = ldfrag(a + e0);
        const bf16x8 vb = ldfrag(b + e0);
        bf16x8 vc, vd;
        if constexpr (NS >= 3) vc = ldfrag(c + e0);
        if constexpr (NS >= 4) vd = ldfrag(d + e0);
        u16 r[8];
        #pragma unroll
        for (int e = 0; e < 8; ++e) {
            float s = (float)va[e] + (float)vb[e];
            if constexpr (NS >= 3) s += (float)vc[e];
            if constexpr (NS >= 4) s += (float)vd[e];
            r[e] = f2bf(s);
        }
        *reinterpret_cast<uint4*>(o + e0) = *reinterpret_cast<uint4*>(r);
    }
}

// ---------------------------------------------------------------------------
// Fused K+V transpose: grid 2048 blocks; blocks [0,1024) transpose K
// (-> KT), blocks [1024,2048) transpose V (-> VT). Tiled XOR-swizzled LDS.
// ---------------------------------------------------------------------------
__global__ __launch_bounds__(256) void tp_kv2(
    const u16* __restrict__ kin, u16* __restrict__ kout,
    const u16* __restrict__ vin, u16* __restrict__ vout)
{
    __shared__ u16 t[64][80];
    const int which = (blockIdx.x >> 10) & 1;
    const int bx    = blockIdx.x & 1023;
    const u16* in_  = which ? vin  : kin;
    u16*       out_ = which ? vout : kout;
    const int tid = threadIdx.x;
    const int bh  = bx >> 5;
    const int tt  = bx & 31;
    const size_t base = (size_t)bh * 131072;
    const int C         = which ? 64 : 2048;
    const int r0        = which ? tt * 64 : 0;
    const int c0        = which ? 0 : tt * 64;
    const int outstride = which ? 2048 : 64;
    const u16* in = in_ + base;
    u16* out      = out_ + base;

    #pragma unroll
    for (int half = 0; half < 2; ++half) {
        const int rr = (tid >> 3) + half * 32;
        const int cb = tid & 7;
        const int cbs = cb ^ ((rr >> 3) & 7);
        *reinterpret_cast<uint4*>(&t[rr][cbs * 8]) =
            *reinterpret_cast<const uint4*>(in + (size_t)(r0 + rr) * C + c0 + cb * 8);
    }
    __syncthreads();
    #pragma unroll
    for (int half = 0; half < 2; ++half) {
        const int c  = (tid >> 3) + half * 32;
        const int rb = tid & 7;
        u16 vv[8];
        #pragma unroll
        for (int e = 0; e < 8; ++e) {
            const int r = rb * 8 + e;
            const int cbs2 = (c >> 3) ^ ((r >> 3) & 7);
            vv[e] = t[r][cbs2 * 8 + (c & 7)];
        }
        *reinterpret_cast<uint4*>(out + (size_t)(c0 + c) * outstride + r0 + rb * 8) =
            *reinterpret_cast<uint4*>(vv);
    }
}

// ---------------------------------------------------------------------------
// Fused attention (R20, FROZEN). 1024 threads = 16 waves, wave w = head w.
// i-tile 64, j-tile 32, 2-barrier schedule, exp2 builtin, packed-f16 softmax.
// Cross-head sum: uniform over all 1024 threads, one (i,jp) point each,
// b32 slab reads. V fragments issued just after barrier 1 so their global
// latency hides under the sum phase.
// ---------------------------------------------------------------------------
__global__ __launch_bounds__(1024) void attn_fused(
    const u16* __restrict__ Qb, const u16* __restrict__ KT,
    const u16* __restrict__ VT, u16* __restrict__ O0,
    u16* __restrict__ O1, u16* __restrict__ O2, u16* __restrict__ O3,
    int jsplit)
{
    __shared__ unsigned expS[16][64][20];  // [head][i][jp] f16x2  (80 KB)
    __shared__ unsigned rcpS[64][20];      // [i][jp] f16x2 of 1/sum (5 KB)

    const int tid  = threadIdx.x;
    const int w    = tid >> 6;        // head
    const int lane = tid & 63;
    const int fm   = lane & 15;
    const int g    = lane >> 4;
    const int fk   = g * 8;
    const int g4   = g * 4;
    const int g2   = g * 2;

    int b, it, js;
    u16* Ob;
    if (jsplit == 4) {
        const int grp = blockIdx.x & 7;
        b  = grp >> 2;
        js = grp & 3;
        it = blockIdx.x >> 3;                 // 0..31
        Ob = (js == 0) ? O0 : (js == 1) ? O1 : (js == 2) ? O2 : O3;
    } else if (jsplit == 2) {
        const int grp = blockIdx.x & 3;
        b  = grp >> 1;
        js = grp & 1;
        it = blockIdx.x >> 2;
        Ob = js ? O1 : O0;
    } else {
        b  = blockIdx.x >> 5;
        it = blockIdx.x & 31;
        js = 0;
        Ob = O0;
    }
    const int jlen  = 2048 / jsplit;
    const int jbase = js * jlen;
    const int i0    = it * 64;
    const size_t hb = ((size_t)b * 2048 + (size_t)w * 128) * 1024;

    // Q fragments (f16): 4 m-blocks x 2 k-steps (loop-invariant)
    f16x8 qa[4][2];
    #pragma unroll
    for (int m = 0; m < 4; ++m)
        #pragma unroll
        for (int kb = 0; kb < 2; ++kb)
            qa[m][kb] = ldfrag16(Qb + hb + (size_t)(i0 + m * 16 + fm) * 64 + kb * 32 + fk);

    f32x4 oacc[4][4] = {};   // 64 x 64 O tile per wave

    const int nt  = jlen >> 5;

    // ---- QK for one j-tile of 32 -> E writes (kf[2][2], st[2], b64 writes) ----
    auto qk_tile = [&](int j0) {
        f16x8 kf[2][2];
        #pragma unroll
        for (int kb = 0; kb < 2; ++kb)
            #pragma unroll
            for (int nb = 0; nb < 2; ++nb)
                kf[kb][nb] = ldfrag16(KT + hb + (size_t)(j0 + nb * 16 + fm) * 64
                                               + kb * 32 + fk);
        #pragma unroll
        for (int m = 0; m < 4; ++m) {
            f32x4 st[2] = {};
            #pragma unroll
            for (int kb = 0; kb < 2; ++kb)
                #pragma unroll
                for (int nb = 0; nb < 2; ++nb)
                    st[nb] = __builtin_amdgcn_mfma_f32_16x16x32_f16(
                        kf[kb][nb], qa[m][kb], st[nb], 0, 0, 0);
            const int row = m * 16 + fm;
            #pragma unroll
            for (int nb = 0; nb < 2; ++nb) {
                uint2 ew2;
                ew2.x = pkrtz(ex2(st[nb][0]), ex2(st[nb][1]));
                ew2.y = pkrtz(ex2(st[nb][2]), ex2(st[nb][3]));
                *reinterpret_cast<uint2*>(&expS[w][row][nb * 8 + g2]) = ew2;
            }
        }
    };

    qk_tile(jbase);   // prologue: E(0)

    for (int t = 0; t < nt; ++t) {
        const int j0 = jbase + (t << 5);
        __syncthreads();   // E(t) complete
        // ---- V frags issued here: latency hides under the sum phase ----
        f16x8 vf[4];
        #pragma unroll
        for (int nb = 0; nb < 4; ++nb)
            vf[nb] = ldfrag16(VT + hb + (size_t)(nb * 16 + fm) * 2048 + j0 + fk);
        // ---- cross-head sum: all 1024 threads, one (i,jp) point each ----
        {
            const int i  = tid >> 4;          // 0..63
            const int jp = tid & 15;          // 0..15
            unsigned eh[16];
            #pragma unroll
            for (int h = 0; h < 16; ++h) eh[h] = expS[h][i][jp];
            const f16x2 s0 = (u2h(eh[0])  + u2h(eh[1]))  + (u2h(eh[2])  + u2h(eh[3]));
            const f16x2 s1 = (u2h(eh[4])  + u2h(eh[5]))  + (u2h(eh[6])  + u2h(eh[7]));
            const f16x2 s2 = (u2h(eh[8])  + u2h(eh[9]))  + (u2h(eh[10]) + u2h(eh[11]));
            const f16x2 s3 = (u2h(eh[12]) + u2h(eh[13])) + (u2h(eh[14]) + u2h(eh[15]));
            const f16x2 ts = (s0 + s1) + (s2 + s3);
            rcpS[i][jp] = pkrtz(__builtin_amdgcn_rcpf((float)ts[0]),
                                __builtin_amdgcn_rcpf((float)ts[1]));
        }
        __syncthreads();   // rcp(t) ready (vmcnt for vf drained here too)
        // ---- P rebuild (packed mul) + PV MFMAs ----
        #pragma unroll
        for (int m = 0; m < 4; ++m) {
            const int row = m * 16 + fm;
            const uint4 ew = *reinterpret_cast<const uint4*>(&expS[w][row][g4]);
            const uint4 rw = *reinterpret_cast<const uint4*>(&rcpS[row][g4]);
            uint4 pw;
            pw.x = h2u(u2h(ew.x) * u2h(rw.x));
            pw.y = h2u(u2h(ew.y) * u2h(rw.y));
            pw.z = h2u(u2h(ew.z) * u2h(rw.z));
            pw.w = h2u(u2h(ew.w) * u2h(rw.w));
            const f16x8 pa = __builtin_bit_cast(f16x8, pw);
            #pragma unroll
            for (int nb = 0; nb < 4; ++nb)
                oacc[m][nb] = __builtin_amdgcn_mfma_f32_16x16x32_f16(
                    pa, vf[nb], oacc[m][nb], 0, 0, 0);
        }
        // ---- QK(t+1) + E(t+1) overwrite (own-wave region; after own E reads) ----
        if (t + 1 < nt) qk_tile(j0 + 32);
    }

    // ---- write O (block-view layout) as bf16 for the final projection ----
    #pragma unroll
    for (int m = 0; m < 4; ++m)
        #pragma unroll
        for (int nb = 0; nb < 4; ++nb)
            #pragma unroll
            for (int r = 0; r < 4; ++r) {
                const int i = i0 + m * 16 + g4 + r;
                Ob[hb + (size_t)i * 64 + nb * 16 + fm] = f2bf(oacc[m][nb][r]);
            }
}

// ---------------------------------------------------------------------------
extern "C" void kernel_launch(void* const* d_in, const int* in_sizes, int n_in,
                              void* d_out, int out_size, void* d_ws, size_t ws_size,
                              hipStream_t stream)
{
    const float* q  = (const float*)d_in[0];
    const float* k  = (const float*)d_in[1];
    const float* v  = (const float*)d_in[2];
    const float* Wq = (const float*)d_in[3];
    const float* bq = (const float*)d_in[4];
    const float* Wk = (const float*)d_in[5];
    const float* bk = (const float*)d_in[6];
    const float* Wv = (const float*)d_in[7];
    const float* bv = (const float*)d_in[8];
    const float* Wc = (const float*)d_in[9];
    const float* bc = (const float*)d_in[10];
    float* out = (float*)d_out;

    const size_t MD = (size_t)4096 * 1024;   // elements per [B*L, D] matrix
    const size_t WM = MD / 4;                // elements per [D, D] weight
    u16* W0 = (u16*)d_ws;        // Q16 -> presummed O
    u16* W1 = W0 + MD;           // K16 -> O0
    u16* W2 = W1 + MD;           // V16 -> O1
    u16* W3 = W2 + MD;           // KT
    u16* W4 = W3 + MD;           // VT
    u16* W5 = W4 + MD;           // O2
    u16* W6 = W5 + MD;           // O3
    // prep (bf16-converted inputs/weights), only used when ws allows:
    u16* qb  = W6 + MD;          //  7*MD
    u16* kb  = qb + MD;          //  8*MD
    u16* vb  = kb + MD;          //  9*MD
    u16* wqb = vb + MD;          // 10*MD
    u16* wkb = wqb + WM;
    u16* wvb = wkb + WM;
    u16* wcb = wvb + WM;         // ends at 11*MD

    int jsplit = 1;
    if      (ws_size >= 7 * MD * sizeof(u16)) jsplit = 4;   // 56 MB
    else if (ws_size >= 5 * MD * sizeof(u16)) jsplit = 2;   // 40 MB
    const bool prep = ws_size >= 11 * MD * sizeof(u16);     // 88 MB

    // Q scale = 1/8 (score scale) * log2(e) (exp -> exp2 folding)
    const float qscale = 0.125f * 1.4426950408889634f;

    // (0) optional one-pass f32 -> bf16 conversion of all GEMM inputs
    if (prep)
        prep_bf16<<<dim3(2048), dim3(256), 0, stream>>>(
            q, k, v, Wq, Wk, Wv, Wc, qb, kb, vb, wqb, wkb, wvb, wcb);

    // (1) fused QKV projections: grid (32,8,3), 512 threads
    if (prep)
        gemm_qkv_t<u16><<<dim3(32, 8, 3), dim3(512), 0, stream>>>(
            qb, kb, vb, wqb, bq, wkb, bk, wvb, bv, W0, W1, W2, qscale);
    else
        gemm_qkv_t<float><<<dim3(32, 8, 3), dim3(512), 0, stream>>>(
            q, k, v, Wq, bq, Wk, bk, Wv, bv, W0, W1, W2, qscale);

    // (2) fused K+V transpose
    tp_kv2<<<dim3(2048), dim3(256), 0, stream>>>(W1, W3, W2, W4);

    // (3) attention
    const int agrid = (jsplit == 4) ? 256 : (jsplit == 2) ? 128 : 64;
    attn_fused<<<dim3(agrid), dim3(1024), 0, stream>>>(
        W0, W3, W4, W1, W2, W5, W6, jsplit);

    // (4) fold partial-O streams once (Q16/W0 is dead after attn)
    const u16* Xf = W1;
    if (jsplit == 4) {
        presum_o<4><<<dim3(2048), dim3(256), 0, stream>>>(W1, W2, W5, W6, W0);
        Xf = W0;
    } else if (jsplit == 2) {
        presum_o<2><<<dim3(2048), dim3(256), 0, stream>>>(W1, W2, nullptr, nullptr, W0);
        Xf = W0;
    }

    // (5) final projection
    if (prep)
        gemm_final_t<u16><<<dim3(32, 8), dim3(512), 0, stream>>>(Xf, wcb, bc, out);
    else
        gemm_final_t<float><<<dim3(32, 8), dim3(512), 0, stream>>>(Xf, Wc, bc, out);
}